// Round 20
// baseline (150.585 us; speedup 1.0000x reference)
//
#include <hip/hip_runtime.h>

#define BS   512
#define NPTS 18
#define CH   2048
#define EPSF 1e-12f
#define BNS  0.9999950000374997f   // 1/sqrt(1+1e-5)

typedef unsigned short ushort_t;
typedef __attribute__((ext_vector_type(8)))  short bfrag;   // 8 bf16 (4 VGPRs)
typedef __attribute__((ext_vector_type(4)))  float f32x4v;  // MFMA 16x16 C/D
typedef __attribute__((ext_vector_type(16))) float f32x16;  // MFMA 32x32 C/D

__device__ inline ushort_t bf16_rne(float f) {
  union { float f; unsigned int u; } c; c.f = f;
  unsigned int u = c.u;
  u += 0x7fffu + ((u >> 16) & 1u);
  return (ushort_t)(u >> 16);
}
__device__ inline float bf16_to_f(ushort_t s) {
  union { float f; unsigned int u; } c; c.u = ((unsigned int)s) << 16;
  return c.f;
}
__device__ inline bfrag cvt8(float4 a, float4 b) {
  bfrag r;
  r[0]=(short)bf16_rne(a.x); r[1]=(short)bf16_rne(a.y);
  r[2]=(short)bf16_rne(a.z); r[3]=(short)bf16_rne(a.w);
  r[4]=(short)bf16_rne(b.x); r[5]=(short)bf16_rne(b.y);
  r[6]=(short)bf16_rne(b.z); r[7]=(short)bf16_rne(b.w);
  return r;
}

// ---------------------------------------------------------------------------
// k_mega: 1024 blocks, INTERLEAVED roles: even blk = per-batch reduce
// (b = blk>>1), odd blk = weight cast (cb = blk>>1). r19's ID-partitioned
// layout ran the latency-bound reduce round and BW-bound cast round
// back-to-back; interleaving mixes them in each resident set so cast
// streaming hides under reduce stalls. Kernel bodies unchanged from r19
// (clean regs: VGPR 52, no spill, LDS 80KB -> 2 blocks/CU).
// ---------------------------------------------------------------------------
__global__ __launch_bounds__(512, 4) void k_mega(
    const float* __restrict__ x, const float* __restrict__ pc,
    const float* __restrict__ w1, const float* __restrict__ b1,
    const float* __restrict__ w2a, const float* __restrict__ b2a,
    const float* __restrict__ g2, const float* __restrict__ be2,
    const float* __restrict__ w2b, const float* __restrict__ b2b,
    const float* __restrict__ wc, const float* __restrict__ w3,
    ushort_t* __restrict__ wc_bf, ushort_t* __restrict__ w3_bf,
    float* __restrict__ d21, float* __restrict__ d11,
    float* __restrict__ d22, float* __restrict__ d12,
    ushort_t* __restrict__ u_pre, float* __restrict__ dec_out)
{
  const int blk = blockIdx.x, tid = threadIdx.x;

  if (blk & 1) {
    // ---- cast role: cb in [0,512), 8 float4/thread over wc then w3 ----
    const int cb = blk >> 1;
    const int n4 = CH*CH/4;           // 1048576
    #pragma unroll
    for (int k = 0; k < 8; k++) {
      int gid = (cb*8 + k)*512 + tid;      // < 2*n4 exactly
      const float* src; ushort_t* dst; int i;
      if (gid < n4) { src = wc; dst = wc_bf; i = gid; }
      else          { src = w3; dst = w3_bf; i = gid - n4; }
      float4 v = ((const float4*)src)[i];
      ushort4 o;
      o.x = bf16_rne(v.x); o.y = bf16_rne(v.y);
      o.z = bf16_rne(v.z); o.w = bf16_rne(v.w);
      ((ushort4*)dst)[i] = o;
    }
    return;
  }

  // ---- reduce role: one block per batch. LDS = 73728 + 8192 = 81920 B ----
  __shared__ __align__(16) ushort_t IMG[18*CH];   // 73728 B (bf16 x, swizzled)
  __shared__ __align__(16) float F[2048];         // 8192 B flat small-array region
  float* Gt     = F;          // 4*378 = 1512   (Gt[0] becomes combined G/l1)
  float* l2part = F + 1512;   // 4*15 = 60
  float* l2s    = F + 1572;   // 54
  float* z1s    = F + 1626;   // 54
  float* z2s    = F + 1680;   // 54
  float* encs   = F + 1734;   // 54
  float* ycs    = F + 1788;   // 18
  float* xcs    = F + 1806;   // 18
  float* n1inv  = F + 1824;   // 18
  float* n2inv  = F + 1842;   // 18
  float* rinvS  = F + 1860;   // 18
  float* colinv = F + 1878;   // 3   (end 1881 < 2048)

  const int b = blk >> 1, lane = tid & 63, wv = tid >> 6;

  // ---- Phase A: stage x (18x2048) as swizzled bf16; 9 pairs/thread ----
  {
    const float4* x4 = (const float4*)x + (size_t)b*9216;
    #pragma unroll
    for (int k = 0; k < 9; k++) {
      int p = k*512 + tid;                        // 16B-pair index, < 4608
      float4 a = x4[2*p], c = x4[2*p + 1];
      int row = p >> 8;
      *(bfrag*)((char*)IMG + ((p*16) ^ ((row & 7) << 4))) = cvt8(a, c);
    }
  }
  __syncthreads();   // B1

  if (wv < 4) {
    // ---- Gram + l1: wave wv handles ch quarter [512*wv, +512), ONE acc ----
    const int rc = lane & 31, kh = lane >> 5;
    const int arow = (rc < NPTS) ? rc : (NPTS-1);
    const int amsk = (arow & 7) << 4;
    const int abase = arow*4096;
    const bool isw = (rc >= NPTS) && (rc < NPTS+3);
    const int wrow = isw ? (rc - NPTS) : 0;
    const float* wp = w1 + (size_t)wrow*CH + wv*512 + kh*8;
    f32x16 acc = {0.f,0.f,0.f,0.f,0.f,0.f,0.f,0.f,0.f,0.f,0.f,0.f,0.f,0.f,0.f,0.f};
    #pragma unroll 4
    for (int j = 0; j < 32; j++) {
      const int kb = (wv*512 + j*16 + kh*8)*2;    // byte col
      bfrag av = *(const bfrag*)((const char*)IMG + ((abase + kb) ^ amsk));
      bfrag bv = av;
      if (isw) bv = cvt8(*(const float4*)(wp + j*16), *(const float4*)(wp + j*16 + 4));
      acc = __builtin_amdgcn_mfma_f32_32x32x16_bf16(av, bv, acc, 0, 0, 0);
    }
    // C/D layout: col = lane&31, row = (reg&3) + 8*(reg>>2) + 4*(lane>>5)
    #pragma unroll
    for (int r = 0; r < 16; r++) {
      int orow = (r & 3) + 8*(r >> 2) + 4*kh;
      if (orow < NPTS && rc < 21) Gt[wv*378 + orow*21 + rc] = acc[r];
    }
  } else {
    // ---- z2: 4 waves, wave owns 5/5/5/3 points x FULL 2048 channels ----
    const int zid = wv - 4;
    const int p0 = zid*5;
    const int np = (zid == 3) ? 3 : 5;
    const float* pcb = pc + (size_t)b*NPTS*4 + p0*4;
    float pq[5][4];
    #pragma unroll
    for (int j = 0; j < 5; j++) {
      int jj = (j < np) ? j : 0;
      pq[j][0] = pcb[jj*4+0]; pq[j][1] = pcb[jj*4+1];
      pq[j][2] = pcb[jj*4+2]; pq[j][3] = pcb[jj*4+3];
    }
    float acc[5][3];
    #pragma unroll
    for (int j = 0; j < 5; j++) { acc[j][0]=0.f; acc[j][1]=0.f; acc[j][2]=0.f; }
    #pragma unroll 2
    for (int it = 0; it < 32; it++) {
      int c = it*64 + lane;
      const float4 wa = *(const float4*)(w2a + (size_t)c*4);
      float bb = b2a[c], gg = g2[c]*BNS, be = be2[c];
      float wb0 = w2b[c], wb1 = w2b[CH+c], wb2 = w2b[2*CH+c];
      #pragma unroll
      for (int j = 0; j < 5; j++) {
        float v = fmaf(pq[j][3], wa.w, fmaf(pq[j][2], wa.z,
                  fmaf(pq[j][1], wa.y, fmaf(pq[j][0], wa.x, bb))));
        float h = fmaxf(fmaf(v, gg, be), 0.f);
        acc[j][0] = fmaf(h, wb0, acc[j][0]);
        acc[j][1] = fmaf(h, wb1, acc[j][1]);
        acc[j][2] = fmaf(h, wb2, acc[j][2]);
      }
    }
    #pragma unroll
    for (int j = 0; j < 5; j++) {
      if (j < np) {
        #pragma unroll
        for (int k = 0; k < 3; k++) {
          float v = acc[j][k];
          #pragma unroll
          for (int off = 32; off; off >>= 1) v += __shfl_xor(v, off);
          if (lane == 0) l2part[zid*15 + j*3 + k] = v;
        }
      }
    }
  }
  __syncthreads();   // B2

  // ---- combine partials (G in place over Gt[0]); l2 is single-source ----
  if (tid < 378) {
    F[tid] = (F[tid] + F[378+tid]) + (F[756+tid] + F[1134+tid]);
  } else if (tid < 432) {
    int t = tid - 378;
    int p = t/3, k = t - 3*p, zid = p/5, pp = p - 5*zid;
    l2s[t] = l2part[zid*15 + pp*3 + k] + b2b[k];
  } else if (tid >= 448 && tid < 466) {
    int n = tid - 448;
    const float* p = pc + (size_t)b*NPTS*4 + n*4;
    ycs[n] = p[0] + floorf(p[2]*0.5f);
    xcs[n] = p[1] + floorf(p[3]*0.5f);
  }
  __syncthreads();   // B3
  float* sGl = F;    // combined [18][21]: cols 0-17 = G, 18-20 = l1

  // ---- softmaxes, norms, dec ----
  if (tid < NPTS) {
    int n = tid;
    float a0 = sGl[n*21+18] + b1[0], a1 = sGl[n*21+19] + b1[1], a2 = sGl[n*21+20] + b1[2];
    float mx = fmaxf(a0, fmaxf(a1, a2));
    float e0 = expf(a0-mx), e1 = expf(a1-mx), e2 = expf(a2-mx);
    float inv = 1.f/(e0+e1+e2);
    float z10 = e0*inv, z11 = e1*inv, z12 = e2*inv;
    z1s[n*3+0]=z10; z1s[n*3+1]=z11; z1s[n*3+2]=z12;
    n1inv[n] = 1.f/fmaxf(sqrtf(z10*z10+z11*z11+z12*z12), EPSF);

    float c0 = l2s[n*3+0], c1 = l2s[n*3+1], c2 = l2s[n*3+2];
    mx = fmaxf(c0, fmaxf(c1, c2));
    e0 = expf(c0-mx); e1 = expf(c1-mx); e2 = expf(c2-mx);
    inv = 1.f/(e0+e1+e2);
    float z20 = e0*inv, z21 = e1*inv, z22 = e2*inv;
    z2s[n*3+0]=z20; z2s[n*3+1]=z21; z2s[n*3+2]=z22;
    n2inv[n] = 1.f/fmaxf(sqrtf(z20*z20+z21*z21+z22*z22), EPSF);

    float zr0 = z10+z20, zr1 = z11+z21, zr2 = z12+z22;
    float rinvv = 1.f/((zr0+zr1+zr2) + EPSF);
    dec_out[(size_t)b*54 + n*3 + 0] = zr0*rinvv;
    dec_out[(size_t)b*54 + n*3 + 1] = zr1*rinvv;
    dec_out[(size_t)b*54 + n*3 + 2] = zr2*rinvv;

    rinvS[n] = 1.f/fmaxf(sqrtf(sGl[n*21+n]), EPSF);
  }
  __syncthreads();   // B4

  if (tid < 3) {
    float s = 0.f;
    #pragma unroll
    for (int n = 0; n < NPTS; n++) s += z1s[n*3+tid] + z2s[n*3+tid];
    colinv[tid] = 1.f/(s + EPSF);
  }
  if (tid < NPTS*NPTS) {
    int t = tid;
    int n = t/NPTS, mm = t - n*NPTS;
    float dd21 = (z1s[n*3]*z1s[mm*3] + z1s[n*3+1]*z1s[mm*3+1] + z1s[n*3+2]*z1s[mm*3+2])
                 * n1inv[n]*n1inv[mm];
    float dd22 = (z2s[n*3]*z2s[mm*3] + z2s[n*3+1]*z2s[mm*3+1] + z2s[n*3+2]*z2s[mm*3+2])
                 * n2inv[n]*n2inv[mm];
    float dd11 = sGl[n*21+mm] * rinvS[n]*rinvS[mm];
    float dyv = ycs[mm]-ycs[n], dxv = xcs[mm]-xcs[n];
    float r = dxv*dxv + dyv*dyv;
    float dd12 = 1.f - 2.f*((r > 0.f) ? sqrtf(r) : 0.f);
    size_t o = (size_t)b*NPTS*NPTS + t;
    d21[o] = dd21; d11[o] = dd11; d22[o] = dd22; d12[o] = dd12;
  }
  __syncthreads();   // B5
  if (tid < 54) encs[tid] = (z1s[tid]+z2s[tid])*colinv[tid%3];
  __syncthreads();   // B6

  // ---- u_pre[k,c] = sum_n enc[n,k]*x[n,c]; 512 thr x 4 ch from LDS ----
  {
    const int c0 = tid*4;
    float av0[4], av1[4], av2[4];
    #pragma unroll
    for (int j = 0; j < 4; j++) { av0[j]=0.f; av1[j]=0.f; av2[j]=0.f; }
    #pragma unroll 2
    for (int n = 0; n < NPTS; n++) {
      ushort4 xv = *(const ushort4*)((const char*)IMG + ((n*4096 + c0*2) ^ ((n & 7) << 4)));
      float e0 = encs[n*3+0], e1 = encs[n*3+1], e2 = encs[n*3+2];
      float x0 = bf16_to_f(xv.x), x1 = bf16_to_f(xv.y);
      float x2 = bf16_to_f(xv.z), x3 = bf16_to_f(xv.w);
      av0[0]=fmaf(e0,x0,av0[0]); av0[1]=fmaf(e0,x1,av0[1]);
      av0[2]=fmaf(e0,x2,av0[2]); av0[3]=fmaf(e0,x3,av0[3]);
      av1[0]=fmaf(e1,x0,av1[0]); av1[1]=fmaf(e1,x1,av1[1]);
      av1[2]=fmaf(e1,x2,av1[2]); av1[3]=fmaf(e1,x3,av1[3]);
      av2[0]=fmaf(e2,x0,av2[0]); av2[1]=fmaf(e2,x1,av2[1]);
      av2[2]=fmaf(e2,x2,av2[2]); av2[3]=fmaf(e2,x3,av2[3]);
    }
    ushort4 o0, o1, o2;
    o0.x=bf16_rne(av0[0]); o0.y=bf16_rne(av0[1]); o0.z=bf16_rne(av0[2]); o0.w=bf16_rne(av0[3]);
    o1.x=bf16_rne(av1[0]); o1.y=bf16_rne(av1[1]); o1.z=bf16_rne(av1[2]); o1.w=bf16_rne(av1[3]);
    o2.x=bf16_rne(av2[0]); o2.y=bf16_rne(av2[1]); o2.z=bf16_rne(av2[2]); o2.w=bf16_rne(av2[3]);
    *(ushort4*)(u_pre + ((size_t)b*3 + 0)*CH + c0) = o0;
    *(ushort4*)(u_pre + ((size_t)b*3 + 1)*CH + c0) = o1;
    *(ushort4*)(u_pre + ((size_t)b*3 + 2)*CH + c0) = o2;
  }
}

// ---------------------------------------------------------------------------
// gemm1: bf16 MFMA, NOW 128x128 tile (m97-proven shape) -> 192 blocks,
// halves L3 operand re-read traffic (~300 -> ~196 MB) vs 128x64/384.
// dbuf LDS (64 KB -> 2 blocks/CU), one barrier per K-tile, T2 swizzle,
// XCD swizzle (192 % 8 == 0).
// ---------------------------------------------------------------------------
#define GM 1536
#define GK 2048
#define GN 2048

#define STAGE1(buf, k0) { \
    _Pragma("unroll") \
    for (int i = 0; i < 4; i++) \
      __builtin_amdgcn_global_load_lds( \
          (const __attribute__((address_space(1))) void*)(Ag + (size_t)(i*32 + ldrow)*GK + (k0)), \
          (__attribute__((address_space(3))) void*)(&Asm[buf][i*2048 + wv*512]), 16, 0, 0); \
    _Pragma("unroll") \
    for (int i = 0; i < 4; i++) \
      __builtin_amdgcn_global_load_lds( \
          (const __attribute__((address_space(1))) void*)(Bg + (size_t)(i*32 + ldrow)*GK + (k0)), \
          (__attribute__((address_space(3))) void*)(&Bsm[buf][i*2048 + wv*512]), 16, 0, 0); }

__global__ __launch_bounds__(256) void gemm1(
    const ushort_t* __restrict__ A, const ushort_t* __restrict__ B,
    ushort_t* __restrict__ Cout, const float* __restrict__ bias,
    const float* __restrict__ gamma, const float* __restrict__ beta)
{
  __shared__ ushort_t Asm[2][128*64];   // 2 x 16 KB
  __shared__ ushort_t Bsm[2][128*64];   // 2 x 16 KB
  const int tid  = threadIdx.x;
  const int lane = tid & 63, wv = tid >> 6;
  const int wg = (blockIdx.x & 7)*24 + (blockIdx.x >> 3);   // XCD swizzle
  const int mb = wg % (GM/128), nb = wg / (GM/128);
  const int wr = (wv >> 1) * 64, wc = (wv & 1) * 64;   // wave quadrant 64x64

  f32x4v acc[4][4];
  #pragma unroll
  for (int m = 0; m < 4; m++)
    #pragma unroll
    for (int n = 0; n < 4; n++)
      acc[m][n] = (f32x4v){0.f, 0.f, 0.f, 0.f};

  const int ldrow = tid >> 3;                         // 0..31 per 32-row chunk
  const int ldcol = (((tid & 7) ^ (ldrow & 7)) * 8);  // pre-swizzled source col
  const ushort_t* Ag = A + (size_t)(mb*128)*GK + ldcol;
  const ushort_t* Bg = B + (size_t)(nb*128)*GK + ldcol;
  const int r15 = lane & 15, khi = lane >> 4;

  STAGE1(0, 0)
  __syncthreads();
  for (int t = 0; t < GK/64; ++t) {
    const int cur = t & 1;
    if (t < GK/64 - 1) STAGE1(cur ^ 1, (t+1)*64)
    #pragma unroll
    for (int ks = 0; ks < 2; ks++) {
      bfrag af[4], bfv[4];
      #pragma unroll
      for (int m = 0; m < 4; m++) {
        const int ar = wr + m*16 + r15;
        af[m] = *(const bfrag*)(&Asm[cur][ar*64 + ((ks*32 + khi*8) ^ ((ar & 7)*8))]);
      }
      #pragma unroll
      for (int n = 0; n < 4; n++) {
        const int br = wc + n*16 + r15;
        bfv[n] = *(const bfrag*)(&Bsm[cur][br*64 + ((ks*32 + khi*8) ^ ((br & 7)*8))]);
      }
      #pragma unroll
      for (int m = 0; m < 4; m++)
        #pragma unroll
        for (int n = 0; n < 4; n++)
          acc[m][n] = __builtin_amdgcn_mfma_f32_16x16x32_bf16(
              af[m], bfv[n], acc[m][n], 0, 0, 0);
    }
    __syncthreads();   // drains prefetch (mostly complete) + joins waves
  }

  #pragma unroll
  for (int n = 0; n < 4; n++) {
    const int gc = nb*128 + wc + n*16 + r15;
    float bi = bias[gc], ga = gamma[gc]*BNS, be = beta[gc];
    #pragma unroll
    for (int m = 0; m < 4; m++) {
      const int gr0 = mb*128 + wr + m*16 + khi*4;
      #pragma unroll
      for (int r = 0; r < 4; r++) {
        float v = fmaxf(fmaf(acc[m][n][r] + bi, ga, be), 0.f);
        Cout[(size_t)(gr0 + r)*GN + gc] = bf16_rne(v);
      }
    }
  }
}

// ---------------------------------------------------------------------------
// gemm_epi: fused gemm2 + epilogue (r17 version, unchanged). BM=96, BN=64,
// 512 blocks XCD-swizzled, dbuf bf16 operands, dec-combine+BN+ReLU+residual.
// ---------------------------------------------------------------------------
#define STAGE2(buf, k0) { \
    _Pragma("unroll") \
    for (int i = 0; i < 3; i++) { \
      int u = i*256 + tid; \
      int arw = u >> 3, ac8 = u & 7; \
      __builtin_amdgcn_global_load_lds( \
          (const __attribute__((address_space(1))) void*)(Au + (size_t)(mb*96 + arw)*GK + (k0) + ((ac8 ^ (arw & 7))*8)), \
          (__attribute__((address_space(3))) void*)(&A2[buf][u*8]), 16, 0, 0); \
    } \
    _Pragma("unroll") \
    for (int i = 0; i < 2; i++) { \
      int u = i*256 + tid; \
      int brw = u >> 3, bc8 = u & 7; \
      __builtin_amdgcn_global_load_lds( \
          (const __attribute__((address_space(1))) void*)(Bw + (size_t)(nb*64 + brw)*GK + (k0) + ((bc8 ^ (brw & 7))*8)), \
          (__attribute__((address_space(3))) void*)(&B2[buf][u*8]), 16, 0, 0); \
    } }

__global__ __launch_bounds__(256) void gemm_epi(
    const ushort_t* __restrict__ Au, const ushort_t* __restrict__ Bw,
    const float* __restrict__ x, const float* __restrict__ dec,
    const float* __restrict__ b3, const float* __restrict__ g3,
    const float* __restrict__ be3, float* __restrict__ y)
{
  __shared__ ushort_t A2[2][96*64];      // 2 x 12 KB
  __shared__ ushort_t B2[2][64*64];      // 2 x 8 KB
  __shared__ ushort_t Vl[96*68];         // 13056 B (bf16, padded stride)
  __shared__ float decl[32*54];          // 6912 B
  __shared__ float mul_[64], add_[64];   // 512 B
  const int tid = threadIdx.x, lane = tid & 63, wv = tid >> 6;
  const int wg = (blockIdx.x & 7)*64 + (blockIdx.x >> 3);   // XCD swz (512%8==0)
  const int mb = wg & 15, nb = wg >> 4;
  const int wr = (wv >> 1)*48, wc = (wv & 1)*32;
  const int r15 = lane & 15, khi = lane >> 4;

  // stage dec + BN params (read only in epilogue)
  for (int i = tid; i < 32*54; i += 256) decl[i] = dec[(size_t)mb*1728 + i];
  if (tid < 64) {
    float mu = g3[nb*64 + tid]*BNS;
    mul_[tid] = mu;
    add_[tid] = fmaf(b3[nb*64 + tid], mu, be3[nb*64 + tid]);
  }

  f32x4v acc[3][2];
  #pragma unroll
  for (int m = 0; m < 3; m++)
    #pragma unroll
    for (int n = 0; n < 2; n++)
      acc[m][n] = (f32x4v){0.f, 0.f, 0.f, 0.f};

  STAGE2(0, 0)
  __syncthreads();
  for (int t = 0; t < GK/64; ++t) {
    const int cur = t & 1;
    if (t < GK/64 - 1) STAGE2(cur ^ 1, (t+1)*64)
    #pragma unroll
    for (int ks = 0; ks < 2; ks++) {
      bfrag af[3], bfv[2];
      #pragma unroll
      for (int m = 0; m < 3; m++) {
        const int ar = wr + m*16 + r15;
        af[m] = *(const bfrag*)(&A2[cur][ar*64 + ((ks*32 + khi*8) ^ ((ar & 7)*8))]);
      }
      #pragma unroll
      for (int n = 0; n < 2; n++) {
        const int br = wc + n*16 + r15;
        bfv[n] = *(const bfrag*)(&B2[cur][br*64 + ((ks*32 + khi*8) ^ ((br & 7)*8))]);
      }
      #pragma unroll
      for (int m = 0; m < 3; m++)
        #pragma unroll
        for (int n = 0; n < 2; n++)
          acc[m][n] = __builtin_amdgcn_mfma_f32_16x16x32_bf16(
              af[m], bfv[n], acc[m][n], 0, 0, 0);
    }
    __syncthreads();
  }

  // acc -> Vl (bf16, stride 68)
  #pragma unroll
  for (int n = 0; n < 2; n++) {
    const int gcl = wc + n*16 + r15;
    #pragma unroll
    for (int m = 0; m < 3; m++) {
      const int gr0 = wr + m*16 + khi*4;
      #pragma unroll
      for (int r = 0; r < 4; r++)
        Vl[(gr0 + r)*68 + gcl] = bf16_rne(acc[m][n][r]);
    }
  }
  __syncthreads();

  // epilogue: thread -> batch bb = tid>>3, col-group cg = tid&7 (8 cols)
  {
    const int bb = tid >> 3, cg = tid & 7;
    float vr[3][8], mu[8], ad[8];
    #pragma unroll
    for (int k = 0; k < 3; k++) {
      ushort4 v0 = *(const ushort4*)(&Vl[(bb*3 + k)*68 + cg*8]);
      ushort4 v1 = *(const ushort4*)(&Vl[(bb*3 + k)*68 + cg*8 + 4]);
      vr[k][0]=bf16_to_f(v0.x); vr[k][1]=bf16_to_f(v0.y);
      vr[k][2]=bf16_to_f(v0.z); vr[k][3]=bf16_to_f(v0.w);
      vr[k][4]=bf16_to_f(v1.x); vr[k][5]=bf16_to_f(v1.y);
      vr[k][6]=bf16_to_f(v1.z); vr[k][7]=bf16_to_f(v1.w);
    }
    #pragma unroll
    for (int j = 0; j < 8; j++) { mu[j] = mul_[cg*8+j]; ad[j] = add_[cg*8+j]; }

    const size_t rowbase = ((size_t)(mb*32 + bb)*NPTS)*CH + nb*64 + cg*8;
    for (int n = 0; n < NPTS; n++) {
      float d0 = decl[bb*54 + n*3 + 0];
      float d1 = decl[bb*54 + n*3 + 1];
      float d2 = decl[bb*54 + n*3 + 2];
      const float* xr = x + rowbase + (size_t)n*CH;
      float* yr = y + rowbase + (size_t)n*CH;
      #pragma unroll
      for (int cc = 0; cc < 2; cc++) {
        float4 xv = *(const float4*)(xr + cc*4);
        float4 o;
        #pragma unroll
        for (int j = 0; j < 4; j++) {
          int c = cc*4 + j;
          float val = fmaf(d0, vr[0][c], fmaf(d1, vr[1][c], d2*vr[2][c]));
          float res = fmaxf(fmaf(val, mu[c], ad[c]), 0.f);
          ((float*)&o)[j] = res + ((const float*)&xv)[j];
        }
        *(float4*)(yr + cc*4) = o;
      }
    }
  }
}

// ---------------------------------------------------------------------------
extern "C" void kernel_launch(void* const* d_in, const int* in_sizes, int n_in,
                              void* d_out, int out_size, void* d_ws, size_t ws_size,
                              hipStream_t stream) {
  const float* x   = (const float*)d_in[0];
  const float* pc  = (const float*)d_in[1];
  const float* w1  = (const float*)d_in[2];
  const float* b1  = (const float*)d_in[3];
  const float* w2a = (const float*)d_in[4];
  const float* b2a = (const float*)d_in[5];
  const float* g2  = (const float*)d_in[6];
  const float* be2 = (const float*)d_in[7];
  const float* w2b = (const float*)d_in[8];
  const float* b2b = (const float*)d_in[9];
  const float* wc  = (const float*)d_in[10];
  const float* bc  = (const float*)d_in[11];
  const float* gc  = (const float*)d_in[12];
  const float* bec = (const float*)d_in[13];
  const float* w3  = (const float*)d_in[14];
  const float* b3  = (const float*)d_in[15];
  const float* g3  = (const float*)d_in[16];
  const float* be3 = (const float*)d_in[17];

  float* out = (float*)d_out;
  float* y   = out;
  float* d21 = out + (size_t)BS*NPTS*CH;
  float* d11 = d21 + (size_t)BS*NPTS*NPTS;
  float* d22 = d11 + (size_t)BS*NPTS*NPTS;
  float* d12 = d22 + (size_t)BS*NPTS*NPTS;

  // y-region scratch (consumed by gemm1, which does NOT write y):
  char* ybytes = (char*)y;
  ushort_t* u_pre_bf = (ushort_t*)(ybytes + 0);          // 6.29 MB
  ushort_t* wc_bf    = (ushort_t*)(ybytes + 6291456);    // 8.39 MB (end 14.7 MB)

  // d_ws: operands of gemm_epi (which writes y) must NOT live in y.
  ushort_t* u_bf  = (ushort_t*)d_ws;                     // 6.29 MB
  ushort_t* w3_bf = (ushort_t*)((char*)d_ws + 6291456);  // 8.39 MB
  float*    decb  = (float*)((char*)d_ws + 14680064);    // 110 KB (end 14.8 MB)

  k_mega<<<BS*2, 512, 0, stream>>>(x, pc, w1, b1, w2a, b2a, g2, be2,
                                   w2b, b2b, wc, w3, wc_bf, w3_bf,
                                   d21, d11, d22, d12, u_pre_bf, decb);
  gemm1<<<(GM/128)*(GN/128), 256, 0, stream>>>(u_pre_bf, wc_bf, u_bf, bc, gc, bec);
  gemm_epi<<<512, 256, 0, stream>>>(u_bf, w3_bf, x, decb, b3, g3, be3, y);
}

// Round 21
// 127.532 us; speedup vs baseline: 1.1808x; 1.1808x over previous
//
#include <hip/hip_runtime.h>

#define BS   512
#define NPTS 18
#define CH   2048
#define EPSF 1e-12f
#define BNS  0.9999950000374997f   // 1/sqrt(1+1e-5)

typedef unsigned short ushort_t;
typedef __attribute__((ext_vector_type(8)))  short bfrag;   // 8 bf16 (4 VGPRs)
typedef __attribute__((ext_vector_type(4)))  float f32x4v;  // MFMA 16x16 C/D
typedef __attribute__((ext_vector_type(16))) float f32x16;  // MFMA 32x32 C/D

__device__ inline ushort_t bf16_rne(float f) {
  union { float f; unsigned int u; } c; c.f = f;
  unsigned int u = c.u;
  u += 0x7fffu + ((u >> 16) & 1u);
  return (ushort_t)(u >> 16);
}
__device__ inline float bf16_to_f(ushort_t s) {
  union { float f; unsigned int u; } c; c.u = ((unsigned int)s) << 16;
  return c.f;
}
__device__ inline bfrag cvt8(float4 a, float4 b) {
  bfrag r;
  r[0]=(short)bf16_rne(a.x); r[1]=(short)bf16_rne(a.y);
  r[2]=(short)bf16_rne(a.z); r[3]=(short)bf16_rne(a.w);
  r[4]=(short)bf16_rne(b.x); r[5]=(short)bf16_rne(b.y);
  r[6]=(short)bf16_rne(b.z); r[7]=(short)bf16_rne(b.w);
  return r;
}

// ---------------------------------------------------------------------------
// k_mega (r19 exact — measured best 68.5us): 512 threads, (512,4) -> clean
// regs (VGPR 52, no spill), LDS exactly 80KB -> 2 blocks/CU.
// Blocks [0,BS) = per-batch reduce (ID-PARTITIONED, not interleaved: r20
// proved cast-role blocks still reserve the static 80KB LDS, so interleave
// halves resident reduce blocks); [BS,BS+512) = weight casts.
// ---------------------------------------------------------------------------
__global__ __launch_bounds__(512, 4) void k_mega(
    const float* __restrict__ x, const float* __restrict__ pc,
    const float* __restrict__ w1, const float* __restrict__ b1,
    const float* __restrict__ w2a, const float* __restrict__ b2a,
    const float* __restrict__ g2, const float* __restrict__ be2,
    const float* __restrict__ w2b, const float* __restrict__ b2b,
    const float* __restrict__ wc, const float* __restrict__ w3,
    ushort_t* __restrict__ wc_bf, ushort_t* __restrict__ w3_bf,
    float* __restrict__ d21, float* __restrict__ d11,
    float* __restrict__ d22, float* __restrict__ d12,
    ushort_t* __restrict__ u_pre, float* __restrict__ dec_out)
{
  const int blk = blockIdx.x, tid = threadIdx.x;

  if (blk >= BS) {
    // ---- cast region: 512 blocks x 8 float4/thread over wc then w3 ----
    const int cb = blk - BS;
    const int n4 = CH*CH/4;           // 1048576
    #pragma unroll
    for (int k = 0; k < 8; k++) {
      int gid = (cb*8 + k)*512 + tid;      // < 2*n4 exactly
      const float* src; ushort_t* dst; int i;
      if (gid < n4) { src = wc; dst = wc_bf; i = gid; }
      else          { src = w3; dst = w3_bf; i = gid - n4; }
      float4 v = ((const float4*)src)[i];
      ushort4 o;
      o.x = bf16_rne(v.x); o.y = bf16_rne(v.y);
      o.z = bf16_rne(v.z); o.w = bf16_rne(v.w);
      ((ushort4*)dst)[i] = o;
    }
    return;
  }

  // ---- reduce region: one block per batch. LDS = 73728 + 8192 = 81920 B ----
  __shared__ __align__(16) ushort_t IMG[18*CH];   // 73728 B (bf16 x, swizzled)
  __shared__ __align__(16) float F[2048];         // 8192 B flat small-array region
  float* Gt     = F;          // 4*378 = 1512   (Gt[0] becomes combined G/l1)
  float* l2part = F + 1512;   // 4*15 = 60
  float* l2s    = F + 1572;   // 54
  float* z1s    = F + 1626;   // 54
  float* z2s    = F + 1680;   // 54
  float* encs   = F + 1734;   // 54
  float* ycs    = F + 1788;   // 18
  float* xcs    = F + 1806;   // 18
  float* n1inv  = F + 1824;   // 18
  float* n2inv  = F + 1842;   // 18
  float* rinvS  = F + 1860;   // 18
  float* colinv = F + 1878;   // 3   (end 1881 < 2048)

  const int b = blk, lane = tid & 63, wv = tid >> 6;

  // ---- Phase A: stage x (18x2048) as swizzled bf16; 9 pairs/thread ----
  {
    const float4* x4 = (const float4*)x + (size_t)b*9216;
    #pragma unroll
    for (int k = 0; k < 9; k++) {
      int p = k*512 + tid;                        // 16B-pair index, < 4608
      float4 a = x4[2*p], c = x4[2*p + 1];
      int row = p >> 8;
      *(bfrag*)((char*)IMG + ((p*16) ^ ((row & 7) << 4))) = cvt8(a, c);
    }
  }
  __syncthreads();   // B1

  if (wv < 4) {
    // ---- Gram + l1: wave wv handles ch quarter [512*wv, +512), ONE acc ----
    const int rc = lane & 31, kh = lane >> 5;
    const int arow = (rc < NPTS) ? rc : (NPTS-1);
    const int amsk = (arow & 7) << 4;
    const int abase = arow*4096;
    const bool isw = (rc >= NPTS) && (rc < NPTS+3);
    const int wrow = isw ? (rc - NPTS) : 0;
    const float* wp = w1 + (size_t)wrow*CH + wv*512 + kh*8;
    f32x16 acc = {0.f,0.f,0.f,0.f,0.f,0.f,0.f,0.f,0.f,0.f,0.f,0.f,0.f,0.f,0.f,0.f};
    #pragma unroll 4
    for (int j = 0; j < 32; j++) {
      const int kb = (wv*512 + j*16 + kh*8)*2;    // byte col
      bfrag av = *(const bfrag*)((const char*)IMG + ((abase + kb) ^ amsk));
      bfrag bv = av;
      if (isw) bv = cvt8(*(const float4*)(wp + j*16), *(const float4*)(wp + j*16 + 4));
      acc = __builtin_amdgcn_mfma_f32_32x32x16_bf16(av, bv, acc, 0, 0, 0);
    }
    // C/D layout: col = lane&31, row = (reg&3) + 8*(reg>>2) + 4*(lane>>5)
    #pragma unroll
    for (int r = 0; r < 16; r++) {
      int orow = (r & 3) + 8*(r >> 2) + 4*kh;
      if (orow < NPTS && rc < 21) Gt[wv*378 + orow*21 + rc] = acc[r];
    }
  } else {
    // ---- z2: 4 waves, wave owns 5/5/5/3 points x FULL 2048 channels ----
    const int zid = wv - 4;
    const int p0 = zid*5;
    const int np = (zid == 3) ? 3 : 5;
    const float* pcb = pc + (size_t)b*NPTS*4 + p0*4;
    float pq[5][4];
    #pragma unroll
    for (int j = 0; j < 5; j++) {
      int jj = (j < np) ? j : 0;
      pq[j][0] = pcb[jj*4+0]; pq[j][1] = pcb[jj*4+1];
      pq[j][2] = pcb[jj*4+2]; pq[j][3] = pcb[jj*4+3];
    }
    float acc[5][3];
    #pragma unroll
    for (int j = 0; j < 5; j++) { acc[j][0]=0.f; acc[j][1]=0.f; acc[j][2]=0.f; }
    #pragma unroll 2
    for (int it = 0; it < 32; it++) {
      int c = it*64 + lane;
      const float4 wa = *(const float4*)(w2a + (size_t)c*4);
      float bb = b2a[c], gg = g2[c]*BNS, be = be2[c];
      float wb0 = w2b[c], wb1 = w2b[CH+c], wb2 = w2b[2*CH+c];
      #pragma unroll
      for (int j = 0; j < 5; j++) {
        float v = fmaf(pq[j][3], wa.w, fmaf(pq[j][2], wa.z,
                  fmaf(pq[j][1], wa.y, fmaf(pq[j][0], wa.x, bb))));
        float h = fmaxf(fmaf(v, gg, be), 0.f);
        acc[j][0] = fmaf(h, wb0, acc[j][0]);
        acc[j][1] = fmaf(h, wb1, acc[j][1]);
        acc[j][2] = fmaf(h, wb2, acc[j][2]);
      }
    }
    #pragma unroll
    for (int j = 0; j < 5; j++) {
      if (j < np) {
        #pragma unroll
        for (int k = 0; k < 3; k++) {
          float v = acc[j][k];
          #pragma unroll
          for (int off = 32; off; off >>= 1) v += __shfl_xor(v, off);
          if (lane == 0) l2part[zid*15 + j*3 + k] = v;
        }
      }
    }
  }
  __syncthreads();   // B2

  // ---- combine partials (G in place over Gt[0]); l2 is single-source ----
  if (tid < 378) {
    F[tid] = (F[tid] + F[378+tid]) + (F[756+tid] + F[1134+tid]);
  } else if (tid < 432) {
    int t = tid - 378;
    int p = t/3, k = t - 3*p, zid = p/5, pp = p - 5*zid;
    l2s[t] = l2part[zid*15 + pp*3 + k] + b2b[k];
  } else if (tid >= 448 && tid < 466) {
    int n = tid - 448;
    const float* p = pc + (size_t)b*NPTS*4 + n*4;
    ycs[n] = p[0] + floorf(p[2]*0.5f);
    xcs[n] = p[1] + floorf(p[3]*0.5f);
  }
  __syncthreads();   // B3
  float* sGl = F;    // combined [18][21]: cols 0-17 = G, 18-20 = l1

  // ---- softmaxes, norms, dec ----
  if (tid < NPTS) {
    int n = tid;
    float a0 = sGl[n*21+18] + b1[0], a1 = sGl[n*21+19] + b1[1], a2 = sGl[n*21+20] + b1[2];
    float mx = fmaxf(a0, fmaxf(a1, a2));
    float e0 = expf(a0-mx), e1 = expf(a1-mx), e2 = expf(a2-mx);
    float inv = 1.f/(e0+e1+e2);
    float z10 = e0*inv, z11 = e1*inv, z12 = e2*inv;
    z1s[n*3+0]=z10; z1s[n*3+1]=z11; z1s[n*3+2]=z12;
    n1inv[n] = 1.f/fmaxf(sqrtf(z10*z10+z11*z11+z12*z12), EPSF);

    float c0 = l2s[n*3+0], c1 = l2s[n*3+1], c2 = l2s[n*3+2];
    mx = fmaxf(c0, fmaxf(c1, c2));
    e0 = expf(c0-mx); e1 = expf(c1-mx); e2 = expf(c2-mx);
    inv = 1.f/(e0+e1+e2);
    float z20 = e0*inv, z21 = e1*inv, z22 = e2*inv;
    z2s[n*3+0]=z20; z2s[n*3+1]=z21; z2s[n*3+2]=z22;
    n2inv[n] = 1.f/fmaxf(sqrtf(z20*z20+z21*z21+z22*z22), EPSF);

    float zr0 = z10+z20, zr1 = z11+z21, zr2 = z12+z22;
    float rinvv = 1.f/((zr0+zr1+zr2) + EPSF);
    dec_out[(size_t)b*54 + n*3 + 0] = zr0*rinvv;
    dec_out[(size_t)b*54 + n*3 + 1] = zr1*rinvv;
    dec_out[(size_t)b*54 + n*3 + 2] = zr2*rinvv;

    rinvS[n] = 1.f/fmaxf(sqrtf(sGl[n*21+n]), EPSF);
  }
  __syncthreads();   // B4

  if (tid < 3) {
    float s = 0.f;
    #pragma unroll
    for (int n = 0; n < NPTS; n++) s += z1s[n*3+tid] + z2s[n*3+tid];
    colinv[tid] = 1.f/(s + EPSF);
  }
  if (tid < NPTS*NPTS) {
    int t = tid;
    int n = t/NPTS, mm = t - n*NPTS;
    float dd21 = (z1s[n*3]*z1s[mm*3] + z1s[n*3+1]*z1s[mm*3+1] + z1s[n*3+2]*z1s[mm*3+2])
                 * n1inv[n]*n1inv[mm];
    float dd22 = (z2s[n*3]*z2s[mm*3] + z2s[n*3+1]*z2s[mm*3+1] + z2s[n*3+2]*z2s[mm*3+2])
                 * n2inv[n]*n2inv[mm];
    float dd11 = sGl[n*21+mm] * rinvS[n]*rinvS[mm];
    float dyv = ycs[mm]-ycs[n], dxv = xcs[mm]-xcs[n];
    float r = dxv*dxv + dyv*dyv;
    float dd12 = 1.f - 2.f*((r > 0.f) ? sqrtf(r) : 0.f);
    size_t o = (size_t)b*NPTS*NPTS + t;
    d21[o] = dd21; d11[o] = dd11; d22[o] = dd22; d12[o] = dd12;
  }
  __syncthreads();   // B5
  if (tid < 54) encs[tid] = (z1s[tid]+z2s[tid])*colinv[tid%3];
  __syncthreads();   // B6

  // ---- u_pre[k,c] = sum_n enc[n,k]*x[n,c]; 512 thr x 4 ch from LDS ----
  {
    const int c0 = tid*4;
    float av0[4], av1[4], av2[4];
    #pragma unroll
    for (int j = 0; j < 4; j++) { av0[j]=0.f; av1[j]=0.f; av2[j]=0.f; }
    #pragma unroll 2
    for (int n = 0; n < NPTS; n++) {
      ushort4 xv = *(const ushort4*)((const char*)IMG + ((n*4096 + c0*2) ^ ((n & 7) << 4)));
      float e0 = encs[n*3+0], e1 = encs[n*3+1], e2 = encs[n*3+2];
      float x0 = bf16_to_f(xv.x), x1 = bf16_to_f(xv.y);
      float x2 = bf16_to_f(xv.z), x3 = bf16_to_f(xv.w);
      av0[0]=fmaf(e0,x0,av0[0]); av0[1]=fmaf(e0,x1,av0[1]);
      av0[2]=fmaf(e0,x2,av0[2]); av0[3]=fmaf(e0,x3,av0[3]);
      av1[0]=fmaf(e1,x0,av1[0]); av1[1]=fmaf(e1,x1,av1[1]);
      av1[2]=fmaf(e1,x2,av1[2]); av1[3]=fmaf(e1,x3,av1[3]);
      av2[0]=fmaf(e2,x0,av2[0]); av2[1]=fmaf(e2,x1,av2[1]);
      av2[2]=fmaf(e2,x2,av2[2]); av2[3]=fmaf(e2,x3,av2[3]);
    }
    ushort4 o0, o1, o2;
    o0.x=bf16_rne(av0[0]); o0.y=bf16_rne(av0[1]); o0.z=bf16_rne(av0[2]); o0.w=bf16_rne(av0[3]);
    o1.x=bf16_rne(av1[0]); o1.y=bf16_rne(av1[1]); o1.z=bf16_rne(av1[2]); o1.w=bf16_rne(av1[3]);
    o2.x=bf16_rne(av2[0]); o2.y=bf16_rne(av2[1]); o2.z=bf16_rne(av2[2]); o2.w=bf16_rne(av2[3]);
    *(ushort4*)(u_pre + ((size_t)b*3 + 0)*CH + c0) = o0;
    *(ushort4*)(u_pre + ((size_t)b*3 + 1)*CH + c0) = o1;
    *(ushort4*)(u_pre + ((size_t)b*3 + 2)*CH + c0) = o2;
  }
}

// ---------------------------------------------------------------------------
// gemm1: bf16 MFMA, 128x64 tile, 384 blocks (all CUs used; r20 proved
// 128x128@192 blocks leaves 25% of the chip idle). dbuf LDS, one barrier
// per K-tile, T2 swizzle via pre-swizzled global source + XOR'd ds_read.
// ---------------------------------------------------------------------------
#define GM 1536
#define GK 2048
#define GN 2048

#define STAGE(buf, k0) { \
    _Pragma("unroll") \
    for (int i = 0; i < 4; i++) \
      __builtin_amdgcn_global_load_lds( \
          (const __attribute__((address_space(1))) void*)(Ag + (size_t)(i*32 + ldrow)*GK + (k0)), \
          (__attribute__((address_space(3))) void*)(&Asm[buf][i*2048 + wv*512]), 16, 0, 0); \
    _Pragma("unroll") \
    for (int i = 0; i < 2; i++) \
      __builtin_amdgcn_global_load_lds( \
          (const __attribute__((address_space(1))) void*)(Bg + (size_t)(i*32 + ldrow)*GK + (k0)), \
          (__attribute__((address_space(3))) void*)(&Bsm[buf][i*2048 + wv*512]), 16, 0, 0); }

__global__ __launch_bounds__(256) void gemm1(
    const ushort_t* __restrict__ A, const ushort_t* __restrict__ B,
    ushort_t* __restrict__ Cout, const float* __restrict__ bias,
    const float* __restrict__ gamma, const float* __restrict__ beta)
{
  __shared__ ushort_t Asm[2][128*64];   // 2 x 16 KB
  __shared__ ushort_t Bsm[2][64*64];    // 2 x 8 KB
  const int tid  = threadIdx.x;
  const int lane = tid & 63, wv = tid >> 6;
  const int mb = blockIdx.x % (GM/128), nb = blockIdx.x / (GM/128);
  const int wr = (wv >> 1) * 64, wc = (wv & 1) * 32;   // wave: 64x32 of 128x64

  f32x4v acc[4][2];
  #pragma unroll
  for (int m = 0; m < 4; m++)
    #pragma unroll
    for (int n = 0; n < 2; n++)
      acc[m][n] = (f32x4v){0.f, 0.f, 0.f, 0.f};

  const int ldrow = tid >> 3;                         // 0..31 per 32-row chunk
  const int ldcol = (((tid & 7) ^ (ldrow & 7)) * 8);  // pre-swizzled source col
  const ushort_t* Ag = A + (size_t)(mb*128)*GK + ldcol;
  const ushort_t* Bg = B + (size_t)(nb*64)*GK + ldcol;
  const int r15 = lane & 15, khi = lane >> 4;

  STAGE(0, 0)
  __syncthreads();
  for (int t = 0; t < GK/64; ++t) {
    const int cur = t & 1;
    if (t < GK/64 - 1) STAGE(cur ^ 1, (t+1)*64)
    #pragma unroll
    for (int ks = 0; ks < 2; ks++) {
      bfrag af[4], bfv[2];
      #pragma unroll
      for (int m = 0; m < 4; m++) {
        const int ar = wr + m*16 + r15;
        af[m] = *(const bfrag*)(&Asm[cur][ar*64 + ((ks*32 + khi*8) ^ ((ar & 7)*8))]);
      }
      #pragma unroll
      for (int n = 0; n < 2; n++) {
        const int br = wc + n*16 + r15;
        bfv[n] = *(const bfrag*)(&Bsm[cur][br*64 + ((ks*32 + khi*8) ^ ((br & 7)*8))]);
      }
      #pragma unroll
      for (int m = 0; m < 4; m++)
        #pragma unroll
        for (int n = 0; n < 2; n++)
          acc[m][n] = __builtin_amdgcn_mfma_f32_16x16x32_bf16(
              af[m], bfv[n], acc[m][n], 0, 0, 0);
    }
    __syncthreads();   // drains prefetch (mostly complete) + joins waves
  }

  #pragma unroll
  for (int n = 0; n < 2; n++) {
    const int gc = nb*64 + wc + n*16 + r15;
    float bi = bias[gc], ga = gamma[gc]*BNS, be = beta[gc];
    #pragma unroll
    for (int m = 0; m < 4; m++) {
      const int gr0 = mb*128 + wr + m*16 + khi*4;
      #pragma unroll
      for (int r = 0; r < 4; r++) {
        float v = fmaxf(fmaf(acc[m][n][r] + bi, ga, be), 0.f);
        Cout[(size_t)(gr0 + r)*GN + gc] = bf16_rne(v);
      }
    }
  }
}

// ---------------------------------------------------------------------------
// gemm_epi: fused gemm2 + epilogue (r17 version). BM=96, BN=64, 512 blocks
// XCD-swizzled, dbuf bf16 operands, dec-combine + BN + ReLU + residual -> y.
// ---------------------------------------------------------------------------
#define STAGE2(buf, k0) { \
    _Pragma("unroll") \
    for (int i = 0; i < 3; i++) { \
      int u = i*256 + tid; \
      int arw = u >> 3, ac8 = u & 7; \
      __builtin_amdgcn_global_load_lds( \
          (const __attribute__((address_space(1))) void*)(Au + (size_t)(mb*96 + arw)*GK + (k0) + ((ac8 ^ (arw & 7))*8)), \
          (__attribute__((address_space(3))) void*)(&A2[buf][u*8]), 16, 0, 0); \
    } \
    _Pragma("unroll") \
    for (int i = 0; i < 2; i++) { \
      int u = i*256 + tid; \
      int brw = u >> 3, bc8 = u & 7; \
      __builtin_amdgcn_global_load_lds( \
          (const __attribute__((address_space(1))) void*)(Bw + (size_t)(nb*64 + brw)*GK + (k0) + ((bc8 ^ (brw & 7))*8)), \
          (__attribute__((address_space(3))) void*)(&B2[buf][u*8]), 16, 0, 0); \
    } }

__global__ __launch_bounds__(256) void gemm_epi(
    const ushort_t* __restrict__ Au, const ushort_t* __restrict__ Bw,
    const float* __restrict__ x, const float* __restrict__ dec,
    const float* __restrict__ b3, const float* __restrict__ g3,
    const float* __restrict__ be3, float* __restrict__ y)
{
  __shared__ ushort_t A2[2][96*64];      // 2 x 12 KB
  __shared__ ushort_t B2[2][64*64];      // 2 x 8 KB
  __shared__ ushort_t Vl[96*68];         // 13056 B (bf16, padded stride)
  __shared__ float decl[32*54];          // 6912 B
  __shared__ float mul_[64], add_[64];   // 512 B
  const int tid = threadIdx.x, lane = tid & 63, wv = tid >> 6;
  const int wg = (blockIdx.x & 7)*64 + (blockIdx.x >> 3);   // XCD swz (512%8==0)
  const int mb = wg & 15, nb = wg >> 4;
  const int wr = (wv >> 1)*48, wc = (wv & 1)*32;
  const int r15 = lane & 15, khi = lane >> 4;

  // stage dec + BN params (read only in epilogue)
  for (int i = tid; i < 32*54; i += 256) decl[i] = dec[(size_t)mb*1728 + i];
  if (tid < 64) {
    float mu = g3[nb*64 + tid]*BNS;
    mul_[tid] = mu;
    add_[tid] = fmaf(b3[nb*64 + tid], mu, be3[nb*64 + tid]);
  }

  f32x4v acc[3][2];
  #pragma unroll
  for (int m = 0; m < 3; m++)
    #pragma unroll
    for (int n = 0; n < 2; n++)
      acc[m][n] = (f32x4v){0.f, 0.f, 0.f, 0.f};

  STAGE2(0, 0)
  __syncthreads();
  for (int t = 0; t < GK/64; ++t) {
    const int cur = t & 1;
    if (t < GK/64 - 1) STAGE2(cur ^ 1, (t+1)*64)
    #pragma unroll
    for (int ks = 0; ks < 2; ks++) {
      bfrag af[3], bfv[2];
      #pragma unroll
      for (int m = 0; m < 3; m++) {
        const int ar = wr + m*16 + r15;
        af[m] = *(const bfrag*)(&A2[cur][ar*64 + ((ks*32 + khi*8) ^ ((ar & 7)*8))]);
      }
      #pragma unroll
      for (int n = 0; n < 2; n++) {
        const int br = wc + n*16 + r15;
        bfv[n] = *(const bfrag*)(&B2[cur][br*64 + ((ks*32 + khi*8) ^ ((br & 7)*8))]);
      }
      #pragma unroll
      for (int m = 0; m < 3; m++)
        #pragma unroll
        for (int n = 0; n < 2; n++)
          acc[m][n] = __builtin_amdgcn_mfma_f32_16x16x32_bf16(
              af[m], bfv[n], acc[m][n], 0, 0, 0);
    }
    __syncthreads();
  }

  // acc -> Vl (bf16, stride 68)
  #pragma unroll
  for (int n = 0; n < 2; n++) {
    const int gcl = wc + n*16 + r15;
    #pragma unroll
    for (int m = 0; m < 3; m++) {
      const int gr0 = wr + m*16 + khi*4;
      #pragma unroll
      for (int r = 0; r < 4; r++)
        Vl[(gr0 + r)*68 + gcl] = bf16_rne(acc[m][n][r]);
    }
  }
  __syncthreads();

  // epilogue: thread -> batch bb = tid>>3, col-group cg = tid&7 (8 cols)
  {
    const int bb = tid >> 3, cg = tid & 7;
    float vr[3][8], mu[8], ad[8];
    #pragma unroll
    for (int k = 0; k < 3; k++) {
      ushort4 v0 = *(const ushort4*)(&Vl[(bb*3 + k)*68 + cg*8]);
      ushort4 v1 = *(const ushort4*)(&Vl[(bb*3 + k)*68 + cg*8 + 4]);
      vr[k][0]=bf16_to_f(v0.x); vr[k][1]=bf16_to_f(v0.y);
      vr[k][2]=bf16_to_f(v0.z); vr[k][3]=bf16_to_f(v0.w);
      vr[k][4]=bf16_to_f(v1.x); vr[k][5]=bf16_to_f(v1.y);
      vr[k][6]=bf16_to_f(v1.z); vr[k][7]=bf16_to_f(v1.w);
    }
    #pragma unroll
    for (int j = 0; j < 8; j++) { mu[j] = mul_[cg*8+j]; ad[j] = add_[cg*8+j]; }

    const size_t rowbase = ((size_t)(mb*32 + bb)*NPTS)*CH + nb*64 + cg*8;
    for (int n = 0; n < NPTS; n++) {
      float d0 = decl[bb*54 + n*3 + 0];
      float d1 = decl[bb*54 + n*3 + 1];
      float d2 = decl[bb*54 + n*3 + 2];
      const float* xr = x + rowbase + (size_t)n*CH;
      float* yr = y + rowbase + (size_t)n*CH;
      #pragma unroll
      for (int cc = 0; cc < 2; cc++) {
        float4 xv = *(const float4*)(xr + cc*4);
        float4 o;
        #pragma unroll
        for (int j = 0; j < 4; j++) {
          int c = cc*4 + j;
          float val = fmaf(d0, vr[0][c], fmaf(d1, vr[1][c], d2*vr[2][c]));
          float res = fmaxf(fmaf(val, mu[c], ad[c]), 0.f);
          ((float*)&o)[j] = res + ((const float*)&xv)[j];
        }
        *(float4*)(yr + cc*4) = o;
      }
    }
  }
}

// ---------------------------------------------------------------------------
extern "C" void kernel_launch(void* const* d_in, const int* in_sizes, int n_in,
                              void* d_out, int out_size, void* d_ws, size_t ws_size,
                              hipStream_t stream) {
  const float* x   = (const float*)d_in[0];
  const float* pc  = (const float*)d_in[1];
  const float* w1  = (const float*)d_in[2];
  const float* b1  = (const float*)d_in[3];
  const float* w2a = (const float*)d_in[4];
  const float* b2a = (const float*)d_in[5];
  const float* g2  = (const float*)d_in[6];
  const float* be2 = (const float*)d_in[7];
  const float* w2b = (const float*)d_in[8];
  const float* b2b = (const float*)d_in[9];
  const float* wc  = (const float*)d_in[10];
  const float* bc  = (const float*)d_in[11];
  const float* gc  = (const float*)d_in[12];
  const float* bec = (const float*)d_in[13];
  const float* w3  = (const float*)d_in[14];
  const float* b3  = (const float*)d_in[15];
  const float* g3  = (const float*)d_in[16];
  const float* be3 = (const float*)d_in[17];

  float* out = (float*)d_out;
  float* y   = out;
  float* d21 = out + (size_t)BS*NPTS*CH;
  float* d11 = d21 + (size_t)BS*NPTS*NPTS;
  float* d22 = d11 + (size_t)BS*NPTS*NPTS;
  float* d12 = d22 + (size_t)BS*NPTS*NPTS;

  // y-region scratch (consumed by gemm1, which does NOT write y):
  char* ybytes = (char*)y;
  ushort_t* u_pre_bf = (ushort_t*)(ybytes + 0);          // 6.29 MB
  ushort_t* wc_bf    = (ushort_t*)(ybytes + 6291456);    // 8.39 MB (end 14.7 MB)

  // d_ws: operands of gemm_epi (which writes y) must NOT live in y.
  ushort_t* u_bf  = (ushort_t*)d_ws;                     // 6.29 MB
  ushort_t* w3_bf = (ushort_t*)((char*)d_ws + 6291456);  // 8.39 MB
  float*    decb  = (float*)((char*)d_ws + 14680064);    // 110 KB (end 14.8 MB)

  k_mega<<<BS + 512, 512, 0, stream>>>(x, pc, w1, b1, w2a, b2a, g2, be2,
                                       w2b, b2b, wc, w3, wc_bf, w3_bf,
                                       d21, d11, d22, d12, u_pre_bf, decb);
  gemm1<<<(GM/128)*(GN/64), 256, 0, stream>>>(u_pre_bf, wc_bf, u_bf, bc, gc, bec);
  gemm_epi<<<512, 256, 0, stream>>>(u_bf, w3_bf, x, decb, b3, g3, be3, y);
}